// Round 2
// baseline (1671.739 us; speedup 1.0000x reference)
//
#include <hip/hip_runtime.h>

// CTC loss forward, matching tf.nn.ctc_loss semantics from the JAX reference.
// B=64, T=2000, V=128, L=200 -> S=401 extended states. One wave per batch
// element; alpha fully register-resident (7 states/lane), no barriers.

#define NEGF (-1.0e9f)

constexpr int B_ = 64;
constexpr int T_ = 2000;
constexpr int V_ = 128;
constexpr int L_ = 200;
constexpr int S_ = 2 * L_ + 1;   // 401
constexpr int NS = 7;            // states per lane (64*7 = 448 >= 401)

__device__ __forceinline__ float lae3(float a0, float a1, float a2) {
    // logaddexp of three values; safe when some/all are NEGF (stays very negative).
    float m = fmaxf(fmaxf(a0, a1), a2);
    float r = __expf(a0 - m) + __expf(a1 - m) + __expf(a2 - m);
    return m + __logf(r);
}

__global__ __launch_bounds__(64) void ctc_fwd_kernel(
        const float* __restrict__ logits,   // [B, T, V]
        const int*   __restrict__ labels,   // [B, L]
        float* __restrict__ out)            // [1] mean loss
{
    const int b    = blockIdx.x;
    const int lane = threadIdx.x;

    const float* lg    = logits + (size_t)b * T_ * V_;
    const int*   lab_b = labels + b * L_;

    // --- per-lane static state: extended labels + skip flags ---
    int  lab[NS];
    bool skip[NS];
    bool valid[NS];
#pragma unroll
    for (int j = 0; j < NS; ++j) {
        const int s = lane * NS + j;
        valid[j] = (s < S_);
        lab[j]   = V_ - 1;   // blank
        skip[j]  = false;
        if (s < S_ && (s & 1)) {
            const int li = s >> 1;
            lab[j] = lab_b[li];
            if (s >= 3) skip[j] = (lab_b[li] != lab_b[li - 1]);
        }
    }

    float a[NS];
#pragma unroll
    for (int j = 0; j < NS; ++j) a[j] = NEGF;

    // ---- t = 0 (peeled): alpha0 from log-softmax of row 0 ----
    float v0 = lg[lane];
    float v1 = lg[64 + lane];
    {
        float m = fmaxf(v0, v1);
#pragma unroll
        for (int off = 32; off; off >>= 1) m = fmaxf(m, __shfl_xor(m, off));
        float e = __expf(v0 - m) + __expf(v1 - m);
#pragma unroll
        for (int off = 32; off; off >>= 1) e += __shfl_xor(e, off);
        const float lse = m + __logf(e);
        if (lane == 0) {
            // s=0 -> blank (idx 127 lives in v1 lane 63), s=1 -> labels[0]
            const int i1 = lab[1];
            const float g0 = __shfl(v1, 63);          // handled below via gather
            (void)g0;
            // direct: a[0] = lp[blank], a[1] = lp[labels[0]]
            a[0] = 0.0f; a[1] = 0.0f;                 // placeholders, set after gathers
        }
        // gathers must be wave-uniform (shuffles), so compute for all lanes
        float lp0, lp1;
        {
            const int idx = V_ - 1;                   // blank = 127
            const float ga = __shfl(v0, idx & 63);
            const float gb = __shfl(v1, idx & 63);
            lp0 = ((idx < 64) ? ga : gb) - lse;
        }
        {
            const int idx = __shfl(lab[1], 0);        // labels[0], uniform
            const float ga = __shfl(v0, idx & 63);
            const float gb = __shfl(v1, idx & 63);
            lp1 = ((idx < 64) ? ga : gb) - lse;
        }
        if (lane == 0) { a[0] = lp0; a[1] = lp1; }
    }

    // Prime row t=1.
    v0 = lg[V_ + lane];
    v1 = lg[V_ + 64 + lane];

    for (int t = 1; t < T_; ++t) {
        // Prefetch next row while we compute on the current one.
        float n0 = 0.0f, n1 = 0.0f;
        if (t + 1 < T_) {
            const size_t base = (size_t)(t + 1) * V_;
            n0 = lg[base + lane];
            n1 = lg[base + 64 + lane];
        }

        // log-softmax denominator over V=128 via wave butterfly.
        float m = fmaxf(v0, v1);
#pragma unroll
        for (int off = 32; off; off >>= 1) m = fmaxf(m, __shfl_xor(m, off));
        float e = __expf(v0 - m) + __expf(v1 - m);
#pragma unroll
        for (int off = 32; off; off >>= 1) e += __shfl_xor(e, off);
        const float lse = m + __logf(e);

        // Gather lp at this lane's extended labels (cross-lane shuffles).
        float lp[NS];
#pragma unroll
        for (int j = 0; j < NS; ++j) {
            const int idx = lab[j];
            const float g0 = __shfl(v0, idx & 63);
            const float g1 = __shfl(v1, idx & 63);
            lp[j] = ((idx < 64) ? g0 : g1) - lse;
        }

        // Boundary values from previous lane.
        float p_last  = __shfl_up(a[NS - 1], 1);  // alpha[s-1] for j==0
        float p_last2 = __shfl_up(a[NS - 2], 1);  // alpha[s-2] for j==0
        if (lane == 0) { p_last = NEGF; p_last2 = NEGF; }

        float na[NS];
        na[0] = lae3(a[0], p_last, skip[0] ? p_last2 : NEGF) + lp[0];
        na[1] = lae3(a[1], a[0],   skip[1] ? p_last  : NEGF) + lp[1];
#pragma unroll
        for (int j = 2; j < NS; ++j)
            na[j] = lae3(a[j], a[j - 1], skip[j] ? a[j - 2] : NEGF) + lp[j];
#pragma unroll
        for (int j = 0; j < NS; ++j) a[j] = valid[j] ? na[j] : NEGF;

        v0 = n0; v1 = n1;
    }

    // ll = logaddexp(alpha[S-1], alpha[S-2]); loss_b = -ll; out = mean_b loss_b.
    constexpr int LN1 = (S_ - 1) / NS, J1 = (S_ - 1) % NS;  // s=400 -> lane 57, j 1
    constexpr int LN2 = (S_ - 2) / NS, J2 = (S_ - 2) % NS;  // s=399 -> lane 57, j 0
    const float aS1 = __shfl(a[J1], LN1);
    const float aS2 = __shfl(a[J2], LN2);
    if (lane == 0) {
        const float mm = fmaxf(aS1, aS2);
        const float ll = mm + __logf(__expf(aS1 - mm) + __expf(aS2 - mm));
        atomicAdd(out, -ll * (1.0f / (float)B_));
    }
}

extern "C" void kernel_launch(void* const* d_in, const int* in_sizes, int n_in,
                              void* d_out, int out_size, void* d_ws, size_t ws_size,
                              hipStream_t stream) {
    const float* logits = (const float*)d_in[0];
    const int*   labels = (const int*)d_in[1];
    float* out = (float*)d_out;

    // d_out is poisoned before every launch; zero it for the atomic mean.
    hipMemsetAsync(out, 0, sizeof(float), stream);
    ctc_fwd_kernel<<<B_, 64, 0, stream>>>(logits, labels, out);
}

// Round 5
// 1039.033 us; speedup vs baseline: 1.6089x; 1.6089x over previous
//
#include <hip/hip_runtime.h>
#include <hip/hip_fp16.h>

// CTC loss forward, two-kernel scheme (log-domain scan = verified round-2 math):
//   ctc_prep: parallel. lp_ext[b][t][s] = log_softmax(logits[b,t])[ext[s]],
//             fp16, padded to 512 states/row (pad lp = -1e4), in d_ws.
//   ctc_scan: serial over T. Round-2 lae3 recursion, 8 states/lane,
//             PF=16 register prefetch with clamped indices (no tail parity).
// Fallback to the verified round-2 single-kernel if ws too small.

#define NEGF  (-1.0e9f)
#define PADLP (-1.0e4f)

constexpr int B_ = 64, T_ = 2000, V_ = 128, L_ = 200;
constexpr int S_ = 2 * L_ + 1;   // 401
constexpr int NSP = 8;           // states per lane, 64*8 = 512 >= 401

// ------------------------- Kernel A: parallel precompute -------------------------
__global__ __launch_bounds__(256) void ctc_prep(
        const float* __restrict__ logits,   // [B, T, V]
        const int*   __restrict__ labels,   // [B, L]
        __half*      __restrict__ P)        // [B, T, 512] fp16 lp_ext
{
    const int wave = threadIdx.x >> 6;
    const int lane = threadIdx.x & 63;
    const int row  = blockIdx.x * 4 + wave;            // row = b*T + t
    const int b    = row / T_;
    const float* lg    = logits + (size_t)row * V_;
    const int*   lab_b = labels + b * L_;

    const float v0 = lg[lane];
    const float v1 = lg[64 + lane];

    float m = fmaxf(v0, v1);
#pragma unroll
    for (int off = 32; off; off >>= 1) m = fmaxf(m, __shfl_xor(m, off));
    float e = __expf(v0 - m) + __expf(v1 - m);
#pragma unroll
    for (int off = 32; off; off >>= 1) e += __shfl_xor(e, off);
    const float lse = m + __logf(e);

    union { int4 v; __half h[8]; } u;
#pragma unroll
    for (int j = 0; j < NSP; ++j) {
        const int s  = lane * NSP + j;
        const int li = ((s >> 1) < L_) ? (s >> 1) : (L_ - 1);   // clamp (pad only)
        const int idx = (s & 1) ? lab_b[li] : (V_ - 1);         // odd->label, even->blank
        const float g0 = __shfl(v0, idx & 63);
        const float g1 = __shfl(v1, idx & 63);
        const float g  = (idx < 64) ? g0 : g1;
        u.h[j] = __float2half((s < S_) ? (g - lse) : PADLP);
    }
    ((int4*)P)[(size_t)row * 64 + lane] = u.v;
}

// ------------------------- Kernel B: serial log-domain scan -------------------------
__device__ __forceinline__ float lae2(float a0, float a1) {
    float m = fmaxf(a0, a1);
    return m + __logf(__expf(a0 - m) + __expf(a1 - m));
}
__device__ __forceinline__ float lae3(float a0, float a1, float a2) {
    float m = fmaxf(fmaxf(a0, a1), a2);
    return m + __logf(__expf(a0 - m) + __expf(a1 - m) + __expf(a2 - m));
}

__global__ __launch_bounds__(64) void ctc_scan(
        const __half* __restrict__ P,       // [B, T, 512]
        const int*    __restrict__ labels,  // [B, L]
        float* __restrict__ out)            // [1]
{
    const int b    = blockIdx.x;
    const int lane = threadIdx.x;
    const int* lab_b = labels + b * L_;

    // Skip flags for the 4 odd states of this lane (even states never skip).
    // State s = 8*lane + j; skip iff s>=3 and labels[s>>1] != labels[(s>>1)-1].
    bool sk1 = false, sk3 = false, sk5 = false, sk7 = false;
    {
        const int s1 = lane * NSP + 1;
        if (s1 >= 3 && s1 < S_) sk1 = (lab_b[s1 >> 1] != lab_b[(s1 >> 1) - 1]);
        const int s3 = lane * NSP + 3;
        if (s3 < S_)            sk3 = (lab_b[s3 >> 1] != lab_b[(s3 >> 1) - 1]);
        const int s5 = lane * NSP + 5;
        if (s5 < S_)            sk5 = (lab_b[s5 >> 1] != lab_b[(s5 >> 1) - 1]);
        const int s7 = lane * NSP + 7;
        if (s7 < S_)            sk7 = (lab_b[s7 >> 1] != lab_b[(s7 >> 1) - 1]);
    }

    const int4* Pr = (const int4*)P + (size_t)b * T_ * 64 + lane;

    float a[NSP];
    {   // t = 0 init: alpha0 = lp_row0 at states 0,1 (lane 0), else NEG.
        union { int4 v; __half h[8]; } u;
        u.v = Pr[0];
#pragma unroll
        for (int j = 0; j < NSP; ++j)
            a[j] = (lane == 0 && j < 2) ? __half2float(u.h[j]) : NEGF;
    }

    auto stepf = [&](int4 r) {
        union { int4 v; __half h[8]; } u;
        u.v = r;
        float lp[NSP];
#pragma unroll
        for (int j = 0; j < NSP; ++j) lp[j] = __half2float(u.h[j]);
        float am1 = __shfl_up(a[7], 1);      // alpha[s-1] for j==0 == alpha[s-2] for j==1
        if (lane == 0) am1 = NEGF;
        float na[NSP];
        na[0] = lae2(a[0], am1)                        + lp[0];
        na[1] = lae3(a[1], a[0], sk1 ? am1  : NEGF)    + lp[1];
        na[2] = lae2(a[2], a[1])                       + lp[2];
        na[3] = lae3(a[3], a[2], sk3 ? a[1] : NEGF)    + lp[3];
        na[4] = lae2(a[4], a[3])                       + lp[4];
        na[5] = lae3(a[5], a[4], sk5 ? a[3] : NEGF)    + lp[5];
        na[6] = lae2(a[6], a[5])                       + lp[6];
        na[7] = lae3(a[7], a[6], sk7 ? a[5] : NEGF)    + lp[7];
#pragma unroll
        for (int j = 0; j < NSP; ++j) a[j] = na[j];
    };

    constexpr int PF = 16;
    int4 buf[PF];
#pragma unroll
    for (int i = 0; i < PF; ++i) buf[i] = Pr[(size_t)(1 + i) * 64];   // rows 1..16

    int t = 1;
    for (; t + PF <= T_; t += PF) {       // last iteration t=1969 covers rows ..1984
#pragma unroll
        for (int i = 0; i < PF; ++i) {
            const int4 cur = buf[i];
            int nt = t + i + PF;          // row needed 16 steps from now
            nt = (nt < T_) ? nt : (T_ - 1);   // clamp: clamped slots never consumed
            buf[i] = Pr[(size_t)nt * 64];
            stepf(cur);
        }
    }
    // Tail: rows t .. T-1 (t = 1985 -> 15 steps, buf[0..14]).
#pragma unroll
    for (int i = 0; i < PF; ++i) {
        if (t + i < T_) stepf(buf[i]);
    }

    // ll = logaddexp(alpha[400], alpha[399]); s=400 -> lane 50 j0, s=399 -> lane 49 j7.
    const float aS1 = __shfl(a[0], 50);
    const float aS2 = __shfl(a[7], 49);
    if (lane == 0) {
        atomicAdd(out, -lae2(aS1, aS2) * (1.0f / (float)B_));
    }
}

// ------------------------- Fallback (verified round-2 kernel) -------------------------
__global__ __launch_bounds__(64) void ctc_fwd_fallback(
        const float* __restrict__ logits,
        const int*   __restrict__ labels,
        float* __restrict__ out)
{
    const int b    = blockIdx.x;
    const int lane = threadIdx.x;
    const float* lg    = logits + (size_t)b * T_ * V_;
    const int*   lab_b = labels + b * L_;

    constexpr int NS = 7;
    int  lab[NS]; bool skip[NS]; bool valid[NS];
#pragma unroll
    for (int j = 0; j < NS; ++j) {
        const int s = lane * NS + j;
        valid[j] = (s < S_); lab[j] = V_ - 1; skip[j] = false;
        if (s < S_ && (s & 1)) {
            const int li = s >> 1;
            lab[j] = lab_b[li];
            if (s >= 3) skip[j] = (lab_b[li] != lab_b[li - 1]);
        }
    }
    float a[NS];
#pragma unroll
    for (int j = 0; j < NS; ++j) a[j] = NEGF;

    float v0 = lg[lane], v1 = lg[64 + lane];
    for (int t = 0; t < T_; ++t) {
        float n0 = 0.f, n1 = 0.f;
        if (t + 1 < T_) {
            const size_t base = (size_t)(t + 1) * V_;
            n0 = lg[base + lane]; n1 = lg[base + 64 + lane];
        }
        float m = fmaxf(v0, v1);
#pragma unroll
        for (int off = 32; off; off >>= 1) m = fmaxf(m, __shfl_xor(m, off));
        float e = __expf(v0 - m) + __expf(v1 - m);
#pragma unroll
        for (int off = 32; off; off >>= 1) e += __shfl_xor(e, off);
        const float lse = m + __logf(e);

        float lp[NS];
#pragma unroll
        for (int j = 0; j < NS; ++j) {
            const int idx = lab[j];
            const float g0 = __shfl(v0, idx & 63);
            const float g1 = __shfl(v1, idx & 63);
            lp[j] = ((idx < 64) ? g0 : g1) - lse;
        }
        if (t == 0) {
            if (lane == 0) { a[0] = lp[0]; a[1] = lp[1]; }
        } else {
            float p_last  = __shfl_up(a[NS - 1], 1);
            float p_last2 = __shfl_up(a[NS - 2], 1);
            if (lane == 0) { p_last = NEGF; p_last2 = NEGF; }
            float na[NS];
            na[0] = lae3(a[0], p_last, skip[0] ? p_last2 : NEGF) + lp[0];
            na[1] = lae3(a[1], a[0],   skip[1] ? p_last  : NEGF) + lp[1];
#pragma unroll
            for (int j = 2; j < NS; ++j)
                na[j] = lae3(a[j], a[j - 1], skip[j] ? a[j - 2] : NEGF) + lp[j];
#pragma unroll
            for (int j = 0; j < NS; ++j) a[j] = valid[j] ? na[j] : NEGF;
        }
        v0 = n0; v1 = n1;
    }
    constexpr int LN1 = (S_ - 1) / NS, J1 = (S_ - 1) % NS;
    constexpr int LN2i = (S_ - 2) / NS, J2 = (S_ - 2) % NS;
    const float aS1 = __shfl(a[J1], LN1);
    const float aS2 = __shfl(a[J2], LN2i);
    if (lane == 0) {
        const float mm = fmaxf(aS1, aS2);
        const float ll = mm + __logf(__expf(aS1 - mm) + __expf(aS2 - mm));
        atomicAdd(out, -ll * (1.0f / (float)B_));
    }
}

// ------------------------- launcher -------------------------
extern "C" void kernel_launch(void* const* d_in, const int* in_sizes, int n_in,
                              void* d_out, int out_size, void* d_ws, size_t ws_size,
                              hipStream_t stream) {
    const float* logits = (const float*)d_in[0];
    const int*   labels = (const int*)d_in[1];
    float* out = (float*)d_out;

    hipMemsetAsync(out, 0, sizeof(float), stream);

    const size_t needP = (size_t)B_ * T_ * (64 * NSP) * sizeof(__half);  // 131 MB
    if (ws_size >= needP) {
        __half* P = (__half*)d_ws;
        ctc_prep<<<B_ * T_ / 4, 256, 0, stream>>>(logits, labels, P);
        ctc_scan<<<B_, 64, 0, stream>>>(P, labels, out);
    } else {
        ctc_fwd_fallback<<<B_, 64, 0, stream>>>(logits, labels, out);
    }
}